// Round 6
// baseline (5221.129 us; speedup 1.0000x reference)
//
#include <hip/hip_runtime.h>
#include <math.h>

#define H      128
#define NPATH  8192
#define TLEN   512
#define BP     16            // paths per block
#define NTHR   512           // 8 waves; wave w: M-tile rows 16w..16w+15

typedef short bf16x8 __attribute__((ext_vector_type(8)));
typedef float f32x4  __attribute__((ext_vector_type(4)));

#define MFMA(a,b,c) __builtin_amdgcn_mfma_f32_16x16x32_bf16((a),(b),(c),0,0,0)

// ---- LDS byte offsets (total 21.5 KB -> 2 blocks/CU) ----
#define O_BFH   0            // h1f hi [16 path][128 k] bf16 swz (reused for c2 hi)
#define O_BFL   4096         // h1f lo (reused c2 lo)
#define O_BGH   8192         // h1g hi
#define O_BGL   12288        // h1g lo
#define O_PF    16384        // f partials    [8 wave][16 path] float2
#define O_PRAW  17408
#define O_PCORR 18432
#define O_TS    19456        // ts [512] fp32
#define SMEM_BYTES (O_TS + TLEN*4)   // 21504 B

__device__ __forceinline__ float bf2f(unsigned v){ return __uint_as_float(v << 16); }
__device__ __forceinline__ unsigned short f2bf(float f){   // RNE (outputs)
  unsigned u = __float_as_uint(f);
  return (unsigned short)((u + 0x7fffu + ((u >> 16) & 1u)) >> 16);
}
__device__ __forceinline__ float ldany(const void* p, long long i, bool isbf){
  return isbf ? bf2f(((const unsigned short*)p)[i]) : ((const float*)p)[i];
}
__device__ __forceinline__ unsigned short ldbf(const void* p, long long i, bool isbf){
  return isbf ? ((const unsigned short*)p)[i] : f2bf(((const float*)p)[i]);
}
__device__ __forceinline__ float fsig(float x){
  return __builtin_amdgcn_rcpf(1.0f + __expf(-x));
}
__device__ __forceinline__ float fsilu(float x){ return x * fsig(x); }
__device__ __forceinline__ float fsilud(float x){
  float s = fsig(x); return s * (1.0f + x * (1.0f - s));
}
__device__ __forceinline__ float fsoftplus(float x){
  if (x > 15.0f) return x;
  return __logf(1.0f + __expf(x));
}
// truncation split of 2 floats -> packed hi pair, packed lo pair (hi+lo ~= x to 2^-24 rel)
__device__ __forceinline__ void splitpk(float x0, float x1, unsigned& hipk, unsigned& lopk){
  unsigned u0 = __float_as_uint(x0), u1 = __float_as_uint(x1);
  unsigned h0 = u0 & 0xffff0000u, h1 = u1 & 0xffff0000u;
  hipk = (u0 >> 16) | h1;
  float l0 = x0 - __uint_as_float(h0);
  float l1 = x1 - __uint_as_float(h1);
  lopk = (__float_as_uint(l0) >> 16) | (__float_as_uint(l1) & 0xffff0000u);
}
// byte offset of bf16 (row, col) in a [16][128] chunk-swizzled buffer
__device__ __forceinline__ int physB(int row, int col){
  return (row << 8) + ((((col >> 3) ^ (row & 15)) << 4) | ((col & 7) << 1));
}
__device__ __forceinline__ bf16x8 ldfrag(const char* base, int row, int col){
  union { uint4 u; bf16x8 b; } v;
  v.u = *(const uint4*)(base + physB(row, col));
  return v.b;
}

__global__ __launch_bounds__(NTHR, 4)
void GeneratorSDE_kernel(const void* __restrict__ y0, const void* __restrict__ ts,
                         const void* __restrict__ dW,
                         const void* __restrict__ fw1, const void* __restrict__ fb1,
                         const void* __restrict__ fw2, const void* __restrict__ fb2,
                         const void* __restrict__ fw3, const void* __restrict__ fb3,
                         const void* __restrict__ gw1, const void* __restrict__ gb1,
                         const void* __restrict__ gw2, const void* __restrict__ gb2,
                         const void* __restrict__ gw3, const void* __restrict__ gb3,
                         void* __restrict__ out)
{
  extern __shared__ char sm[];
  const int tid  = threadIdx.x;
  const int lane = tid & 63;
  const int w    = tid >> 6;       // wave 0..7: M-tile rows 16w..16w+15
  const int m16  = lane & 15;      // path for B/C frags; A row-in-tile
  const int q    = lane >> 4;      // 0..3
  const int gpb  = blockIdx.x * BP;
  const int net  = w & 1;          // S0: 0 -> drift, 1 -> diffusion
  const int k8   = (w >> 1)*32 + q*8;  // S0 k-slice (8 neurons)
  const int gp   = gpb + m16;      // this lane's path (global)

  const bool isbf = (((const unsigned*)ts)[1] != 0x3f800000u);

  // ---- ts -> LDS ----
  for (int e = tid; e < TLEN; e += NTHR)
    ((float*)(sm + O_TS))[e] = ldany(ts, e, isbf);

  // ---- A-operand weight fragments: gathered straight from GLOBAL (once) ----
  bf16x8 afr[4], agr[4], abr[4];
  #pragma unroll
  for (int kt = 0; kt < 4; ++kt){
    int colk = kt*32 + q*8;
    union { bf16x8 v; unsigned short u[8]; } ua, ug, ub;
    #pragma unroll
    for (int j = 0; j < 8; ++j){
      ua.u[j] = ldbf(fw2, (long long)(colk + j)*H + 16*w + m16, isbf);  // fw2^T[m][k]
      ug.u[j] = ldbf(gw2, (long long)(colk + j)*H + 16*w + m16, isbf);  // gw2^T[m][k]
      ub.u[j] = ldbf(gw2, (long long)(16*w + m16)*H + colk + j, isbf);  // gw2[k][n]
    }
    afr[kt] = ua.v; agr[kt] = ug.v; abr[kt] = ub.v;
  }

  // ---- head/bwd row regs: nr = 16w + 4q + r ----
  float w3f0[4], w3f1[4], w3g0[4], w3g1[4], fb2r[4], gb2r[4], gw1b0[4], gw1b1[4], gb1b[4];
  #pragma unroll
  for (int r = 0; r < 4; ++r){
    int nr = 16*w + (q << 2) + r;
    w3f0[r]  = ldany(fw3, 2*nr + 0, isbf);
    w3f1[r]  = ldany(fw3, 2*nr + 1, isbf);
    w3g0[r]  = ldany(gw3, 2*nr + 0, isbf);
    w3g1[r]  = ldany(gw3, 2*nr + 1, isbf);
    gw1b0[r] = ldany(gw1, nr,       isbf);
    gw1b1[r] = ldany(gw1, H + nr,   isbf);
    gb1b[r]  = ldany(gb1, nr,       isbf);
    fb2r[r]  = ldany(fb2, nr,       isbf);
    gb2r[r]  = ldany(gb2, nr,       isbf);
  }
  // ---- S0 layer-1 slice, spread folded: h = y0*(w0+w2) + y1*(w1-w2) + b ----
  float wr0[8], wr1[8], brg[8];
  #pragma unroll
  for (int kk = 0; kk < 8; ++kk){
    int k = k8 + kk;
    if (net == 0){
      float a = ldany(fw1, k, isbf), b = ldany(fw1, H + k, isbf), c = ldany(fw1, 2*H + k, isbf);
      wr0[kk] = a + c; wr1[kk] = b - c; brg[kk] = ldany(fb1, k, isbf);
    } else {
      wr0[kk] = ldany(gw1, k, isbf); wr1[kk] = ldany(gw1, H + k, isbf);
      brg[kk] = ldany(gb1, k, isbf);
    }
  }
  const float fb3r0 = ldany(fb3, 0, isbf), fb3r1 = ldany(fb3, 1, isbf);
  const float gb3r0 = ldany(gb3, 0, isbf), gb3r1 = ldany(gb3, 1, isbf);

  // ---- path state (redundant across the 8 waves / 4 q-groups sharing a path) ----
  float yc0 = ldany(y0, (long long)gp*2 + 0, isbf);
  float yc1 = ldany(y0, (long long)gp*2 + 1, isbf);
  float2 dwc, dwn;
  {
    long long e = (long long)gp * 2;                 // t = 0
    if (isbf){ unsigned u = *(const unsigned*)((const unsigned short*)dW + e);
               dwc = make_float2(bf2f(u & 0xffffu), bf2f(u >> 16)); }
    else       dwc = *(const float2*)((const float*)dW + e);
  }
  if (w == 0 && lane < 16){
    size_t r = (size_t)gp * TLEN;
    if (isbf) ((unsigned*)out)[r] = (unsigned)f2bf(yc0) | ((unsigned)f2bf(yc1) << 16);
    else      ((float2*)out)[r]   = make_float2(yc0, yc1);
  }
  __syncthreads();   // ts staged

  const float* TSf = (const float*)(sm + O_TS);

  for (int t = 0; t < TLEN - 1; ++t){
    float dt = TSf[t+1] - TSf[t];
    float sqdt = sqrtf(dt);

    // prefetch next-step dW
    {
      int tn = (t + 1 <= TLEN - 2) ? t + 1 : TLEN - 2;
      long long e = ((long long)tn * NPATH + gp) * 2;
      if (isbf){ unsigned u = *(const unsigned*)((const unsigned short*)dW + e);
                 dwn = make_float2(bf2f(u & 0xffffu), bf2f(u >> 16)); }
      else       dwn = *(const float2*)((const float*)dW + e);
    }

    // ---- S0: layer 1 for (net, path m16, 8 k's), split hi/lo ----
    {
      float v[8];
      #pragma unroll
      for (int kk = 0; kk < 8; ++kk)
        v[kk] = fsilu(brg[kk] + yc0*wr0[kk] + yc1*wr1[kk]);
      unsigned hp[4], lp[4];
      splitpk(v[0], v[1], hp[0], lp[0]);
      splitpk(v[2], v[3], hp[1], lp[1]);
      splitpk(v[4], v[5], hp[2], lp[2]);
      splitpk(v[6], v[7], hp[3], lp[3]);
      char* bh = sm + (net ? O_BGH : O_BFH);
      char* bl = sm + (net ? O_BGL : O_BFL);
      int off = physB(m16, k8);
      *(uint4*)(bh + off) = make_uint4(hp[0], hp[1], hp[2], hp[3]);
      *(uint4*)(bl + off) = make_uint4(lp[0], lp[1], lp[2], lp[3]);
    }
    __syncthreads();                                     // A: acts ready

    // ---- S1: fwd MFMAs (f and g) + head partials ----
    f32x4 az;
    {
      f32x4 acf = (f32x4)0.f, acg = (f32x4)0.f;
      #pragma unroll
      for (int kt = 0; kt < 4; ++kt){
        int colk = kt*32 + q*8;
        bf16x8 xfh = ldfrag(sm + O_BFH, m16, colk);
        bf16x8 xfl = ldfrag(sm + O_BFL, m16, colk);
        acf = MFMA(afr[kt], xfl, acf);
        acf = MFMA(afr[kt], xfh, acf);
        bf16x8 xgh = ldfrag(sm + O_BGH, m16, colk);
        bf16x8 xgl = ldfrag(sm + O_BGL, m16, colk);
        acg = MFMA(agr[kt], xgl, acg);
        acg = MFMA(agr[kt], xgh, acg);
      }
      float pf0 = 0, pf1 = 0, pr0 = 0, pr1 = 0;
      #pragma unroll
      for (int r = 0; r < 4; ++r){
        float vf = fsilu(acf[r] + fb2r[r]);
        pf0 += vf * w3f0[r]; pf1 += vf * w3f1[r];
        float zg = acg[r] + gb2r[r];
        acg[r] = zg;                       // biased z2g for S3
        float vg = fsilu(zg);
        pr0 += vg * w3g0[r]; pr1 += vg * w3g1[r];
      }
      az = acg;
      pf0 += __shfl_xor(pf0, 16, 64); pf0 += __shfl_xor(pf0, 32, 64);
      pf1 += __shfl_xor(pf1, 16, 64); pf1 += __shfl_xor(pf1, 32, 64);
      pr0 += __shfl_xor(pr0, 16, 64); pr0 += __shfl_xor(pr0, 32, 64);
      pr1 += __shfl_xor(pr1, 16, 64); pr1 += __shfl_xor(pr1, 32, 64);
      if (lane < 16){
        *(float2*)(sm + O_PF   + (w*16 + lane)*8) = make_float2(pf0, pf1);
        *(float2*)(sm + O_PRAW + (w*16 + lane)*8) = make_float2(pr0, pr1);
      }
    }
    __syncthreads();                                     // B: partials ready

    // ---- S2': combine raw (redundant per lane) -> g, cr ----
    float g0, g1, dw0, dw1, cr0, cr1;
    {
      float raw0 = gb3r0, raw1 = gb3r1;
      #pragma unroll
      for (int w2 = 0; w2 < 8; ++w2){
        float2 v = *(const float2*)(sm + O_PRAW + (w2*16 + m16)*8);
        raw0 += v.x; raw1 += v.y;
      }
      dw0 = dwc.x * sqdt; dw1 = dwc.y * sqdt;
      float vv0 = 0.5f*(dw0*dw0 - dt), vv1 = 0.5f*(dw1*dw1 - dt);
      float sp0 = fsoftplus(raw0), sp1 = fsoftplus(raw1);
      g0 = fminf(fmaxf(sp0, 1e-4f), 5.0f);
      g1 = fminf(fmaxf(sp1, 1e-4f), 5.0f);
      float m0 = (sp0 > 1e-4f && sp0 < 5.0f) ? 1.0f : 0.0f;
      float m1 = (sp1 > 1e-4f && sp1 < 5.0f) ? 1.0f : 0.0f;
      cr0 = vv0 * (g0 * fsig(raw0) * m0);
      cr1 = vv1 * (g1 * fsig(raw1) * m1);
    }

    // ---- S3: cotangent seed c2 -> BFH/BFL (reuse) ----
    {
      float c2v[4];
      #pragma unroll
      for (int r = 0; r < 4; ++r)
        c2v[r] = (cr0 * w3g0[r] + cr1 * w3g1[r]) * fsilud(az[r]);
      unsigned hp0, lp0, hp1, lp1;
      splitpk(c2v[0], c2v[1], hp0, lp0);
      splitpk(c2v[2], c2v[3], hp1, lp1);
      int off = physB(m16, 16*w + q*4);
      *(uint2*)(sm + O_BFH + off) = make_uint2(hp0, hp1);
      *(uint2*)(sm + O_BFL + off) = make_uint2(lp0, lp1);
    }
    __syncthreads();                                     // D: c2 ready

    // ---- S4: backward MFMA (c1 = gw2 @ c2) + corr head partials ----
    {
      f32x4 acc = (f32x4)0.f;
      #pragma unroll
      for (int kt = 0; kt < 4; ++kt){
        int colk = kt*32 + q*8;
        bf16x8 xh = ldfrag(sm + O_BFH, m16, colk);
        bf16x8 xl = ldfrag(sm + O_BFL, m16, colk);
        acc = MFMA(abr[kt], xl, acc);
        acc = MFMA(abr[kt], xh, acc);
      }
      float pc0 = 0, pc1 = 0;
      #pragma unroll
      for (int r = 0; r < 4; ++r){
        float z1 = gb1b[r] + yc0*gw1b0[r] + yc1*gw1b1[r];
        float u  = acc[r] * fsilud(z1);
        pc0 += u * gw1b0[r]; pc1 += u * gw1b1[r];
      }
      pc0 += __shfl_xor(pc0, 16, 64); pc0 += __shfl_xor(pc0, 32, 64);
      pc1 += __shfl_xor(pc1, 16, 64); pc1 += __shfl_xor(pc1, 32, 64);
      if (lane < 16)
        *(float2*)(sm + O_PCORR + (w*16 + lane)*8) = make_float2(pc0, pc1);
    }
    __syncthreads();                                     // E: corr ready

    // ---- S5: Milstein update (redundant per lane) + output ----
    {
      float f0 = fb3r0, f1 = fb3r1, c0 = 0.f, c1 = 0.f;
      #pragma unroll
      for (int w2 = 0; w2 < 8; ++w2){
        float2 a = *(const float2*)(sm + O_PF    + (w2*16 + m16)*8);
        float2 b = *(const float2*)(sm + O_PCORR + (w2*16 + m16)*8);
        f0 += a.x; f1 += a.y; c0 += b.x; c1 += b.y;
      }
      yc0 += f0*dt + g0*dw0 + c0;
      yc1 += f1*dt + g1*dw1 + c1;
      if (w == 0 && lane < 16){
        size_t r = (size_t)gp * TLEN + (t + 1);
        if (isbf) ((unsigned*)out)[r] = (unsigned)f2bf(yc0) | ((unsigned)f2bf(yc1) << 16);
        else      ((float2*)out)[r]   = make_float2(yc0, yc1);
      }
      dwc = dwn;
    }
  }
}

extern "C" void kernel_launch(void* const* d_in, const int* in_sizes, int n_in,
                              void* d_out, int out_size, void* d_ws, size_t ws_size,
                              hipStream_t stream)
{
  (void)in_sizes; (void)n_in; (void)out_size; (void)d_ws; (void)ws_size;
  hipFuncSetAttribute((const void*)GeneratorSDE_kernel,
                      hipFuncAttributeMaxDynamicSharedMemorySize, SMEM_BYTES);
  GeneratorSDE_kernel<<<dim3(NPATH / BP), dim3(NTHR), SMEM_BYTES, stream>>>(
      d_in[0], d_in[1], d_in[2],
      d_in[3], d_in[4], d_in[5], d_in[6], d_in[7], d_in[8],
      d_in[9], d_in[10], d_in[11], d_in[12], d_in[13], d_in[14],
      d_out);
}